// Round 13
// baseline (172.893 us; speedup 1.0000x reference)
//
#include <hip/hip_runtime.h>
#include <hip/hip_bf16.h>

typedef unsigned short u16;
typedef __bf16 bf16x8 __attribute__((ext_vector_type(8)));
typedef __bf16 bf16x4 __attribute__((ext_vector_type(4)));
typedef float f32x4 __attribute__((ext_vector_type(4)));

#define DEVI __device__ __forceinline__

#if __has_builtin(__builtin_amdgcn_exp2f)
#define EXP2 __builtin_amdgcn_exp2f    // raw v_exp_f32 (args are in [-12,10]: safe)
#else
#define EXP2 exp2f
#endif

// ---- problem constants ----
constexpr int Bn = 8, Nn = 1032, Cn = 768, Hn = 12, HDn = 64;
constexpr int NQPc = 1088;             // khead rows per bh (17 * 64; serves q and m)
constexpr int NVM = 1088;              // m extent (17 m-tiles * 64)
constexpr int MTOT = Bn * Nn;          // 8256
constexpr int MPAD = 8320;             // 65 * 128
constexpr int KVN = 1536;
constexpr int PFXc = 8;
constexpr int NPADQ = NVM - Nn;        // 56 zero-padded m positions
constexpr float SCALEc = 0.125f;
constexpr float LOG2Ec = 1.4426950408889634f;
constexpr float C1c = SCALEc * LOG2Ec;
constexpr float INV2S2c = 0.02f;
constexpr float K2c = INV2S2c * LOG2Ec;   // gauss exponent scale in exp2 domain

// ---- workspace layout (attn output aliases xb: xb dead before attn writes) ----
constexpr size_t OFF_XB  = 0;
constexpr size_t SZ_XB   = (size_t)MPAD * Cn * 2;             // 12.78 MB
constexpr size_t OFF_AT  = OFF_XB;                            // alias
constexpr size_t OFF_WKV = OFF_XB + SZ_XB;
constexpr size_t SZ_WKV  = (size_t)KVN * Cn * 2;
constexpr size_t OFF_WP  = OFF_WKV + SZ_WKV;
constexpr size_t SZ_WP   = (size_t)Cn * Cn * 2;
constexpr size_t OFF_K   = OFF_WP + SZ_WP;
constexpr size_t SZ_K    = (size_t)Bn * Hn * NQPc * HDn * 2;  // 13.4 MB
constexpr size_t OFF_V   = OFF_K + SZ_K;
constexpr size_t SZ_V    = (size_t)Bn * Hn * HDn * NVM * 2;   // 13.4 MB

DEVI u16 f2bf(float f) {
  __bf16 h = (__bf16)f;                 // hardware cvt, RNE
  return *reinterpret_cast<u16*>(&h);
}

DEVI void glds16(const void* g, void* l) {
  __builtin_amdgcn_global_load_lds((const __attribute__((address_space(1))) void*)g,
                                   (__attribute__((address_space(3))) void*)l, 16, 0, 0);
}

// ---------------- prep: fp32->bf16 + zero pad regions ----------------
__global__ __launch_bounds__(256) void prep_kernel(
    const float* __restrict__ x, const float* __restrict__ wqkv,
    const float* __restrict__ wproj, u16* __restrict__ xb,
    u16* __restrict__ wkvb, u16* __restrict__ wpb,
    u16* __restrict__ khead, u16* __restrict__ vT) {
  const int n1 = MPAD * Cn / 4, n2 = KVN * Cn / 4, n3 = Cn * Cn / 4;
  const int z1 = 96 * 448;             // khead pad rows: 96 bh * 56 rows * 128B/16B
  const int z2 = 6144 * 7;             // vT pad cols
  const int nc = n1 + n2 + n3;
  const int tot = nc + z1 + z2;
  for (int i = blockIdx.x * blockDim.x + threadIdx.x; i < tot; i += gridDim.x * blockDim.x) {
    if (i < nc) {
      const float* src; u16* dst;
      if (i < n1) {
        int e = i * 4;
        src = (e < MTOT * Cn) ? (x + e) : nullptr;
        dst = xb + e;
      } else if (i < n1 + n2) {
        int e = (i - n1) * 4;
        src = wqkv + Cn * Cn + e;               // skip q-weights (q unused)
        dst = wkvb + e;
      } else {
        int e = (i - n1 - n2) * 4;
        src = wproj + e;
        dst = wpb + e;
      }
      float4 f = src ? *(const float4*)src : make_float4(0.f, 0.f, 0.f, 0.f);
      *(ushort4*)dst = make_ushort4(f2bf(f.x), f2bf(f.y), f2bf(f.z), f2bf(f.w));
    } else if (i < nc + z1) {
      int j = i - nc, bh = j / 448, c = j - bh * 448;
      char* dst = (char*)khead + ((size_t)bh * NQPc + Nn) * HDn * 2 + c * 16;
      *(ushort4*)dst = make_ushort4(0, 0, 0, 0);
      *(ushort4*)(dst + 8) = make_ushort4(0, 0, 0, 0);
    } else {
      int j = i - nc - z1, st = j / 7, c = j - st * 7;
      char* dst = (char*)vT + ((size_t)st * NVM + Nn) * 2 + c * 16;
      *(ushort4*)dst = make_ushort4(0, 0, 0, 0);
      *(ushort4*)(dst + 8) = make_ushort4(0, 0, 0, 0);
    }
  }
}

// ---------------- shared 128x128 BK=64 bt-GEMM mainloop (R9 form) -------------
DEVI void gemm_mainloop(const u16* __restrict__ A, const u16* __restrict__ Bm,
                        int m0, int n0, char* sA, char* sB, f32x4 (&acc)[4][4]) {
  const int tid = threadIdx.x, lane = tid & 63, w = tid >> 6;
  const int ln = lane & 15, lg = lane >> 4;
  const int wm = (w >> 1) * 64, wn = (w & 1) * 64;
  for (int kt = 0; kt < 12; ++kt) {
#pragma unroll
    for (int i = 0; i < 4; ++i) {
      const int c = i * 256 + tid, r = c >> 3, cb = c & 7, gcb = cb ^ (r & 7);
      const char* ga = (const char*)(A + (size_t)(m0 + r) * Cn + kt * 64) + gcb * 16;
      glds16(ga, sA + i * 4096 + w * 1024);
      const char* gb = (const char*)(Bm + (size_t)(n0 + r) * Cn + kt * 64) + gcb * 16;
      glds16(gb, sB + i * 4096 + w * 1024);
    }
    __syncthreads();
#pragma unroll
    for (int ks = 0; ks < 2; ++ks) {
      bf16x8 af[4], bfr[4];
#pragma unroll
      for (int s = 0; s < 4; ++s) {
        const int ra = wm + s * 16 + ln;
        af[s] = *(const bf16x8*)(sA + ra * 128 + (((ks * 4 + lg) ^ (ra & 7)) << 4));
        const int rb = wn + s * 16 + ln;
        bfr[s] = *(const bf16x8*)(sB + rb * 128 + (((ks * 4 + lg) ^ (rb & 7)) << 4));
      }
#pragma unroll
      for (int s = 0; s < 4; ++s)
#pragma unroll
        for (int t = 0; t < 4; ++t)
          acc[s][t] = __builtin_amdgcn_mfma_f32_16x16x32_bf16(af[s], bfr[t], acc[s][t], 0, 0, 0);
    }
    __syncthreads();
  }
}

// ---------------- kernel A: kv = x @ w_kv^T + b, split k / v^T ----------------
// 1D grid 780 blocks, bijective XCD chunking. Epilogue: LDS-transpose then
// fully-coalesced 16B stores.
__global__ __launch_bounds__(256) void kv_gemm(
    const u16* __restrict__ xb, const u16* __restrict__ wkvb,
    const float* __restrict__ bqkv, u16* __restrict__ khead, u16* __restrict__ vT) {
  __shared__ __align__(16) char smem[34816];   // mainloop 32KB; epilogue T 34KB
  char* sA = smem;
  char* sB = smem + 16384;
  const int bid = blockIdx.x;                 // 780 = 8*97 + 4
  const int xcd = bid & 7, loc = bid >> 3;
  const int wgid = (xcd < 4) ? xcd * 98 + loc : 392 + (xcd - 4) * 97 + loc;
  const int m0 = (wgid / 12) * 128, n0 = (wgid % 12) * 128;
  f32x4 acc[4][4] = {};
  gemm_mainloop(xb, wkvb, m0, n0, sA, sB, acc);
  const int tid = threadIdx.x, lane = tid & 63, w = tid >> 6;
  const int ln = lane & 15, lg = lane >> 4;
  const int wm = (w >> 1) * 64, wn = (w & 1) * 64;
  const bool isV = (n0 >= Cn);
  u16* T = (u16*)smem;                        // [128][136] u16 (272B rows, 16B-aligned)
  __syncthreads();                            // mainloop LDS reads done
  if (!isV) {
#pragma unroll
    for (int t = 0; t < 4; ++t) {
      const int c = wn + t * 16 + ln;
      const float bias = bqkv[Cn + n0 + c];
#pragma unroll
      for (int s = 0; s < 4; ++s)
#pragma unroll
        for (int r = 0; r < 4; ++r)
          T[(wm + s * 16 + lg * 4 + r) * 136 + c] = f2bf(acc[s][t][r] + bias);
    }
    __syncthreads();
    const int h0 = n0 >> 6;
#pragma unroll
    for (int i = 0; i < 8; ++i) {
      const int runid = w * 64 + i * 8 + (lane >> 3);
      const int mloc = runid >> 1, hh = runid & 1;
      const int m = m0 + mloc;
      if (m < MTOT) {
        const int b = m / Nn, nr = m - b * Nn;
        const int d0 = (lane & 7) * 8;
        *(uint4*)&khead[((size_t)(b * Hn + h0 + hh) * NQPc + nr) * HDn + d0] =
            *(const uint4*)&T[mloc * 136 + hh * 64 + d0];
      }
    }
  } else {
#pragma unroll
    for (int t = 0; t < 4; ++t) {
      const int c = wn + t * 16 + ln;
      const float bias = bqkv[Cn + n0 + c];
#pragma unroll
      for (int s = 0; s < 4; ++s)
#pragma unroll
        for (int r = 0; r < 4; ++r)
          T[c * 136 + wm + s * 16 + lg * 4 + r] = f2bf(acc[s][t][r] + bias);
    }
    __syncthreads();
    const int vch0 = n0 - Cn;
#pragma unroll
    for (int i = 0; i < 8; ++i) {
      const int c = w * 32 + i * 4 + lg;
      const int vch = vch0 + c, h = vch >> 6, d = vch & 63;
      const int m = m0 + ln * 8;
      if (m < MTOT) {
        const int b = m / Nn, nr = m - b * Nn;
        *(uint4*)&vT[((size_t)(b * Hn + h) * HDn + d) * NVM + nr] =
            *(const uint4*)&T[c * 136 + ln * 8];
      }
    }
  }
}

// ---------------- kernel B: fused gauss attention --------------------------
// 768 patch blocks (8 XCD * 96 = 12 bh * 8 qt of 128 patch-q) + 96 prefix
// blocks (XCD-affine: bh = (i&7)*12 + i>>3). K/V read DIRECTLY from global
// (L2-fits per XCD: 3.34 MB < 4 MB; 16-row x 64B fully-used lines) -> no LDS
// staging, ZERO barriers in patch blocks. sP round-trip is wave-local.
__global__ __launch_bounds__(256) void attn_kernel(
    const u16* __restrict__ khead, const u16* __restrict__ vT, u16* __restrict__ attn) {
  __shared__ __align__(16) char smem[20480];   // patch: sP 4x2KB; prefix: +merge
  const int tid = threadIdx.x, lane = tid & 63, w = tid >> 6;
  const int ln = lane & 15, lg = lane >> 4;
  const int bid = blockIdx.x;
  char* sPw = smem + w * 2048;                 // per-wave [16 q][64 m] bf16, XOR-swz

  bf16x8 ones8;
#pragma unroll
  for (int i = 0; i < 8; ++i) ones8[i] = (__bf16)1.0f;

  if (bid < 768) {
    // ================= patch block: 128 patch-q rows, no barriers =========
    const int xcd = bid & 7, loc = bid >> 3;
    const int lid = xcd * 96 + loc;            // 96/XCD = 12 bh * 8 qt
    const int qt = lid & 7, bh = lid >> 3;
    const int qb = PFXc + qt * 128 + w * 32;   // all q valid patch rows

    bf16x8 qf[2][2];
#pragma unroll
    for (int qg = 0; qg < 2; ++qg) {
      const char* qp = (const char*)(khead + ((size_t)bh * NQPc + qb + qg * 16 + ln) * HDn);
#pragma unroll
      for (int kc = 0; kc < 2; ++kc)
        qf[qg][kc] = *(const bf16x8*)(qp + kc * 64 + lg * 16);
    }

    // ---- per-lane gauss state, one set per q-group (registers only) ----
    const float c2 = EXP2(-2.0f * K2c);
    float ajr[2][8];
    float a0[2], a1[2], a2[2], fr[2];
#pragma unroll
    for (int qg = 0; qg < 2; ++qg) {
      const int pq = qt * 128 + w * 32 + qg * 16 + ln;   // 0..1023
      const int iq = pq >> 5, jq = pq & 31;
#pragma unroll
      for (int t = 0; t < 8; ++t) {
        const int jm = (lg * 4 - 8 + (t >> 2) * 16 + (t & 3)) & 31;
        const float d = (float)(jq - jm);
        ajr[qg][t] = EXP2(-d * d * K2c);
      }
      const float d1 = (float)(iq + 1), d0 = (float)iq, dm = (float)(iq - 1);
      a0[qg] = EXP2(-d1 * d1 * K2c) * LOG2Ec;
      a1[qg] = EXP2(-d0 * d0 * K2c) * LOG2Ec;
      a2[qg] = EXP2(-dm * dm * K2c) * LOG2Ec;
      fr[qg] = EXP2((2.0f * (float)iq - 3.0f) * K2c);
    }

    const char* ksrc = (const char*)(khead + (size_t)bh * NQPc * HDn);
    const char* vsrc = (const char*)(vT + (size_t)bh * HDn * NVM);

    f32x4 oacc[4][2] = {};
    f32x4 dacc[2] = {};

    for (int mc = 0; mc < 17; ++mc) {
      const int mb = mc * 64;
      // S^T = K Q: kf direct from global (16 rows x 64B lines, coalesced)
      f32x4 sacc[4][2] = {};
#pragma unroll
      for (int ms = 0; ms < 4; ++ms) {
        const char* kp = ksrc + (size_t)(mb + ms * 16 + ln) * 128 + lg * 16;
        bf16x8 kf0 = *(const bf16x8*)(kp);
        bf16x8 kf1 = *(const bf16x8*)(kp + 64);
        sacc[ms][0] = __builtin_amdgcn_mfma_f32_16x16x32_bf16(kf0, qf[0][0], sacc[ms][0], 0, 0, 0);
        sacc[ms][0] = __builtin_amdgcn_mfma_f32_16x16x32_bf16(kf1, qf[0][1], sacc[ms][0], 0, 0, 0);
        sacc[ms][1] = __builtin_amdgcn_mfma_f32_16x16x32_bf16(kf0, qf[1][0], sacc[ms][1], 0, 0, 0);
        sacc[ms][1] = __builtin_amdgcn_mfma_f32_16x16x32_bf16(kf1, qf[1][1], sacc[ms][1], 0, 0, 0);
      }

      // P = exp2(S*c1 + al*ajr); qg-split through 2 KB sP (wave-local).
      // mc==0: zero gauss for prefix m<8; mc==16: zero for pad m>=1032 -> p=1.
      bf16x8 pf[2][2];
#pragma unroll
      for (int qg = 0; qg < 2; ++qg) {
        const float b0 = (mc == 0) ? 0.f : a0[qg];
        const float b1 = (mc == 16) ? 0.f : a1[qg];
        const float b2 = (mc == 16) ? 0.f : a2[qg];
#pragma unroll
        for (int ms = 0; ms < 4; ++ms) {
          float al;
          if (ms == 0)      al = (lg < 2) ? b0 : b1;
          else if (ms == 1) al = b1;
          else if (ms == 2) al = (lg < 2) ? b1 : b2;
          else              al = b2;
          const int t0 = (ms & 1) * 4;
          const float p0 = EXP2(fmaf(sacc[ms][qg][0], C1c, al * ajr[qg][t0 + 0]));
          const float p1 = EXP2(fmaf(sacc[ms][qg][1], C1c, al * ajr[qg][t0 + 1]));
          const float p2 = EXP2(fmaf(sacc[ms][qg][2], C1c, al * ajr[qg][t0 + 2]));
          const float p3 = EXP2(fmaf(sacc[ms][qg][3], C1c, al * ajr[qg][t0 + 3]));
          bf16x4 pk;
          pk[0] = (__bf16)p0; pk[1] = (__bf16)p1; pk[2] = (__bf16)p2; pk[3] = (__bf16)p3;
          *(bf16x4*)(sPw + ln * 128 + ((ms * 32 + lg * 8) ^ ((ln & 7) << 4))) = pk;
        }
#pragma unroll
        for (int km = 0; km < 2; ++km)
          pf[qg][km] = *(const bf16x8*)(sPw + ln * 128 +
                                        ((km * 64 + lg * 16) ^ ((ln & 7) << 4)));
        a0[qg] = a2[qg];
        a1[qg] = a2[qg] * fr[qg]; fr[qg] *= c2;
        a2[qg] = a1[qg] * fr[qg]; fr[qg] *= c2;
      }

      // O += P V; den += P * ones. vf direct from global (coalesced rows).
      dacc[0] = __builtin_amdgcn_mfma_f32_16x16x32_bf16(pf[0][0], ones8, dacc[0], 0, 0, 0);
      dacc[0] = __builtin_amdgcn_mfma_f32_16x16x32_bf16(pf[0][1], ones8, dacc[0], 0, 0, 0);
      dacc[1] = __builtin_amdgcn_mfma_f32_16x16x32_bf16(pf[1][0], ones8, dacc[1], 0, 0, 0);
      dacc[1] = __builtin_amdgcn_mfma_f32_16x16x32_bf16(pf[1][1], ones8, dacc[1], 0, 0, 0);
#pragma unroll
      for (int ds = 0; ds < 4; ++ds) {
        const char* vp = vsrc + (size_t)(ds * 16 + ln) * (NVM * 2) + mb * 2 + lg * 16;
#pragma unroll
        for (int km = 0; km < 2; ++km) {
          bf16x8 vf = *(const bf16x8*)(vp + km * 64);
          oacc[ds][0] = __builtin_amdgcn_mfma_f32_16x16x32_bf16(pf[0][km], vf, oacc[ds][0], 0, 0, 0);
          oacc[ds][1] = __builtin_amdgcn_mfma_f32_16x16x32_bf16(pf[1][km], vf, oacc[ds][1], 0, 0, 0);
        }
      }
    }

    // dacc[qg][r] = den for q = qb + qg*16 + lg*4 + r (replicated across ln)
    const int b = bh / Hn, h = bh - b * Hn;
#pragma unroll
    for (int qg = 0; qg < 2; ++qg) {
#pragma unroll
      for (int r = 0; r < 4; ++r) {
        const int qo = qb + qg * 16 + lg * 4 + r;   // always < Nn
        const float dinv = 1.0f / (dacc[qg][r] - (float)NPADQ);
#pragma unroll
        for (int ds = 0; ds < 4; ++ds)
          attn[((size_t)(b * Nn + qo)) * Cn + h * HDn + ds * 16 + ln] =
              f2bf(oacc[ds][qg][r] * dinv);
      }
    }
  } else {
    // ================= prefix block: 8 real q rows, m-split over waves ====
    const int i = bid - 768;
    const int bh = (i & 7) * 12 + (i >> 3);    // XCD-affine with patch blocks
    const char* ksrc = (const char*)(khead + (size_t)bh * NQPc * HDn);
    const char* vsrc = (const char*)(vT + (size_t)bh * HDn * NVM);
    const char* qp = (const char*)(khead + ((size_t)bh * NQPc + ln) * HDn);
    bf16x8 qf[2];
    qf[0] = *(const bf16x8*)(qp + lg * 16);
    qf[1] = *(const bf16x8*)(qp + 64 + lg * 16);

    f32x4 oacc[4] = {};
    f32x4 dacc = {};
    for (int mc = w; mc < 17; mc += 4) {       // wave-strided m tiles, no barriers
      const int mb = mc * 64;
      f32x4 sacc[4] = {};
#pragma unroll
      for (int ms = 0; ms < 4; ++ms) {
        const char* kp = ksrc + (size_t)(mb + ms * 16 + ln) * 128 + lg * 16;
        bf16x8 kf0 = *(const bf16x8*)(kp);
        bf16x8 kf1 = *(const bf16x8*)(kp + 64);
        sacc[ms] = __builtin_amdgcn_mfma_f32_16x16x32_bf16(kf0, qf[0], sacc[ms], 0, 0, 0);
        sacc[ms] = __builtin_amdgcn_mfma_f32_16x16x32_bf16(kf1, qf[1], sacc[ms], 0, 0, 0);
      }
#pragma unroll
      for (int ms = 0; ms < 4; ++ms) {
        bf16x4 pk;
        pk[0] = (__bf16)EXP2(sacc[ms][0] * C1c);
        pk[1] = (__bf16)EXP2(sacc[ms][1] * C1c);
        pk[2] = (__bf16)EXP2(sacc[ms][2] * C1c);
        pk[3] = (__bf16)EXP2(sacc[ms][3] * C1c);
        *(bf16x4*)(sPw + ln * 128 + ((ms * 32 + lg * 8) ^ ((ln & 7) << 4))) = pk;
      }
      bf16x8 pf[2];
#pragma unroll
      for (int km = 0; km < 2; ++km)
        pf[km] = *(const bf16x8*)(sPw + ln * 128 + ((km * 64 + lg * 16) ^ ((ln & 7) << 4)));
      dacc = __builtin_amdgcn_mfma_f32_16x16x32_bf16(pf[0], ones8, dacc, 0, 0, 0);
      dacc = __builtin_amdgcn_mfma_f32_16x16x32_bf16(pf[1], ones8, dacc, 0, 0, 0);
#pragma unroll
      for (int ds = 0; ds < 4; ++ds) {
        const char* vp = vsrc + (size_t)(ds * 16 + ln) * (NVM * 2) + mb * 2 + lg * 16;
#pragma unroll
        for (int km = 0; km < 2; ++km) {
          bf16x8 vf = *(const bf16x8*)(vp + km * 64);
          oacc[ds] = __builtin_amdgcn_mfma_f32_16x16x32_bf16(pf[km], vf, oacc[ds], 0, 0, 0);
        }
      }
    }
    // merge partials across waves via LDS (smem: 16KB oacc + 4KB dacc)
    char* sKf = smem;
    char* sVf = smem + 16384;
    __syncthreads();
#pragma unroll
    for (int ds = 0; ds < 4; ++ds)
      *(f32x4*)(sKf + (((w * 4 + ds) * 64 + lane) << 4)) = oacc[ds];
    *(f32x4*)(sVf + ((w * 64 + lane) << 4)) = dacc;
    __syncthreads();
    f32x4 osum = {}, dsum = {};
#pragma unroll
    for (int wp = 0; wp < 4; ++wp) {
      osum += *(const f32x4*)(sKf + (((wp * 4 + w) * 64 + lane) << 4));
      dsum += *(const f32x4*)(sVf + ((wp * 64 + lane) << 4));
    }
    const int b = bh / Hn, h = bh - b * Hn;
#pragma unroll
    for (int r = 0; r < 4; ++r) {
      const int q = lg * 4 + r;
      if (q < PFXc)
        attn[((size_t)(b * Nn + q)) * Cn + h * HDn + w * 16 + ln] =
            f2bf(osum[r] / (dsum[r] - (float)NPADQ));
    }
  }
}

// ---------------- kernel C: out = attn @ w_proj^T + b_proj ----------------
// 1D grid 390 blocks, bijective XCD chunking
__global__ __launch_bounds__(256) void proj_gemm(
    const u16* __restrict__ at, const u16* __restrict__ wpb,
    const float* __restrict__ bproj, float* __restrict__ out) {
  __shared__ __align__(16) char sA[16384];
  __shared__ __align__(16) char sB[16384];
  const int bid = blockIdx.x;                 // 390 = 8*48 + 6
  const int xcd = bid & 7, loc = bid >> 3;
  const int wgid = (xcd < 6) ? xcd * 49 + loc : 294 + (xcd - 6) * 48 + loc;
  const int m0 = (wgid / 6) * 128, n0 = (wgid % 6) * 128;
  f32x4 acc[4][4] = {};
  gemm_mainloop(at, wpb, m0, n0, sA, sB, acc);
  const int tid = threadIdx.x, lane = tid & 63, w = tid >> 6;
  const int ln = lane & 15, lg = lane >> 4;
  const int wm = (w >> 1) * 64, wn = (w & 1) * 64;
#pragma unroll
  for (int t = 0; t < 4; ++t) {
    const int n = n0 + wn + t * 16 + ln;
    const float bias = bproj[n];
#pragma unroll
    for (int s = 0; s < 4; ++s) {
#pragma unroll
      for (int r = 0; r < 4; ++r) {
        const int m = m0 + wm + s * 16 + lg * 4 + r;
        if (m < MTOT) out[(size_t)m * Cn + n] = acc[s][t][r] + bias;
      }
    }
  }
}

extern "C" void kernel_launch(void* const* d_in, const int* in_sizes, int n_in,
                              void* d_out, int out_size, void* d_ws, size_t ws_size,
                              hipStream_t stream) {
  const float* x     = (const float*)d_in[0];
  const float* wqkv  = (const float*)d_in[1];
  const float* bqkv  = (const float*)d_in[2];
  const float* wproj = (const float*)d_in[3];
  const float* bproj = (const float*)d_in[4];
  char* ws = (char*)d_ws;
  u16* xb    = (u16*)(ws + OFF_XB);
  u16* wkvb  = (u16*)(ws + OFF_WKV);
  u16* wpb   = (u16*)(ws + OFF_WP);
  u16* khead = (u16*)(ws + OFF_K);
  u16* vT    = (u16*)(ws + OFF_V);
  u16* attn  = (u16*)(ws + OFF_AT);    // aliases xb (xb dead by then)

  prep_kernel<<<2048, 256, 0, stream>>>(x, wqkv, wproj, xb, wkvb, wpb, khead, vT);
  kv_gemm<<<780, 256, 0, stream>>>(xb, wkvb, bqkv, khead, vT);
  attn_kernel<<<864, 256, 0, stream>>>(khead, vT, attn);
  proj_gemm<<<390, 256, 0, stream>>>(attn, wpb, bproj, (float*)d_out);
}

// Round 14
// 123.576 us; speedup vs baseline: 1.3991x; 1.3991x over previous
//
#include <hip/hip_runtime.h>
#include <hip/hip_bf16.h>

typedef unsigned short u16;
typedef __bf16 bf16x8 __attribute__((ext_vector_type(8)));
typedef __bf16 bf16x4 __attribute__((ext_vector_type(4)));
typedef float f32x4 __attribute__((ext_vector_type(4)));

#define DEVI __device__ __forceinline__

#if __has_builtin(__builtin_amdgcn_exp2f)
#define EXP2 __builtin_amdgcn_exp2f    // raw v_exp_f32 (args are in [-12,10]: safe)
#else
#define EXP2 exp2f
#endif

// ---- problem constants ----
constexpr int Bn = 8, Nn = 1032, Cn = 768, Hn = 12, HDn = 64;
constexpr int NQPc = 1088;             // khead rows per bh (17 * 64; serves q and m)
constexpr int NVM = 1088;              // m extent (17 m-tiles * 64)
constexpr int MTOT = Bn * Nn;          // 8256
constexpr int MPAD = 8320;             // 65 * 128
constexpr int KVN = 1536;
constexpr int PFXc = 8;
constexpr int NPADQ = NVM - Nn;        // 56 zero-padded m positions
constexpr float SCALEc = 0.125f;
constexpr float LOG2Ec = 1.4426950408889634f;
constexpr float C1c = SCALEc * LOG2Ec;
constexpr float INV2S2c = 0.02f;
constexpr float K2c = INV2S2c * LOG2Ec;   // gauss exponent scale in exp2 domain

// ---- workspace layout (attn output aliases xb: xb dead before attn writes) ----
constexpr size_t OFF_XB  = 0;
constexpr size_t SZ_XB   = (size_t)MPAD * Cn * 2;             // 12.78 MB
constexpr size_t OFF_AT  = OFF_XB;                            // alias
constexpr size_t OFF_WKV = OFF_XB + SZ_XB;
constexpr size_t SZ_WKV  = (size_t)KVN * Cn * 2;
constexpr size_t OFF_WP  = OFF_WKV + SZ_WKV;
constexpr size_t SZ_WP   = (size_t)Cn * Cn * 2;
constexpr size_t OFF_K   = OFF_WP + SZ_WP;
constexpr size_t SZ_K    = (size_t)Bn * Hn * NQPc * HDn * 2;  // 13.4 MB
constexpr size_t OFF_V   = OFF_K + SZ_K;
constexpr size_t SZ_V    = (size_t)Bn * Hn * HDn * NVM * 2;   // 13.4 MB

DEVI u16 f2bf(float f) {
  __bf16 h = (__bf16)f;                 // hardware cvt, RNE
  return *reinterpret_cast<u16*>(&h);
}

DEVI void glds16(const void* g, void* l) {
  __builtin_amdgcn_global_load_lds((const __attribute__((address_space(1))) void*)g,
                                   (__attribute__((address_space(3))) void*)l, 16, 0, 0);
}

// ---------------- prep: fp32->bf16 + zero pad regions ----------------
__global__ __launch_bounds__(256) void prep_kernel(
    const float* __restrict__ x, const float* __restrict__ wqkv,
    const float* __restrict__ wproj, u16* __restrict__ xb,
    u16* __restrict__ wkvb, u16* __restrict__ wpb,
    u16* __restrict__ khead, u16* __restrict__ vT) {
  const int n1 = MPAD * Cn / 4, n2 = KVN * Cn / 4, n3 = Cn * Cn / 4;
  const int z1 = 96 * 448;             // khead pad rows: 96 bh * 56 rows * 128B/16B
  const int z2 = 6144 * 7;             // vT pad cols
  const int nc = n1 + n2 + n3;
  const int tot = nc + z1 + z2;
  for (int i = blockIdx.x * blockDim.x + threadIdx.x; i < tot; i += gridDim.x * blockDim.x) {
    if (i < nc) {
      const float* src; u16* dst;
      if (i < n1) {
        int e = i * 4;
        src = (e < MTOT * Cn) ? (x + e) : nullptr;
        dst = xb + e;
      } else if (i < n1 + n2) {
        int e = (i - n1) * 4;
        src = wqkv + Cn * Cn + e;               // skip q-weights (q unused)
        dst = wkvb + e;
      } else {
        int e = (i - n1 - n2) * 4;
        src = wproj + e;
        dst = wpb + e;
      }
      float4 f = src ? *(const float4*)src : make_float4(0.f, 0.f, 0.f, 0.f);
      *(ushort4*)dst = make_ushort4(f2bf(f.x), f2bf(f.y), f2bf(f.z), f2bf(f.w));
    } else if (i < nc + z1) {
      int j = i - nc, bh = j / 448, c = j - bh * 448;
      char* dst = (char*)khead + ((size_t)bh * NQPc + Nn) * HDn * 2 + c * 16;
      *(ushort4*)dst = make_ushort4(0, 0, 0, 0);
      *(ushort4*)(dst + 8) = make_ushort4(0, 0, 0, 0);
    } else {
      int j = i - nc - z1, st = j / 7, c = j - st * 7;
      char* dst = (char*)vT + ((size_t)st * NVM + Nn) * 2 + c * 16;
      *(ushort4*)dst = make_ushort4(0, 0, 0, 0);
      *(ushort4*)(dst + 8) = make_ushort4(0, 0, 0, 0);
    }
  }
}

// ---------------- shared 128x128 BK=64 bt-GEMM mainloop (R9 form) -------------
DEVI void gemm_mainloop(const u16* __restrict__ A, const u16* __restrict__ Bm,
                        int m0, int n0, char* sA, char* sB, f32x4 (&acc)[4][4]) {
  const int tid = threadIdx.x, lane = tid & 63, w = tid >> 6;
  const int ln = lane & 15, lg = lane >> 4;
  const int wm = (w >> 1) * 64, wn = (w & 1) * 64;
  for (int kt = 0; kt < 12; ++kt) {
#pragma unroll
    for (int i = 0; i < 4; ++i) {
      const int c = i * 256 + tid, r = c >> 3, cb = c & 7, gcb = cb ^ (r & 7);
      const char* ga = (const char*)(A + (size_t)(m0 + r) * Cn + kt * 64) + gcb * 16;
      glds16(ga, sA + i * 4096 + w * 1024);
      const char* gb = (const char*)(Bm + (size_t)(n0 + r) * Cn + kt * 64) + gcb * 16;
      glds16(gb, sB + i * 4096 + w * 1024);
    }
    __syncthreads();
#pragma unroll
    for (int ks = 0; ks < 2; ++ks) {
      bf16x8 af[4], bfr[4];
#pragma unroll
      for (int s = 0; s < 4; ++s) {
        const int ra = wm + s * 16 + ln;
        af[s] = *(const bf16x8*)(sA + ra * 128 + (((ks * 4 + lg) ^ (ra & 7)) << 4));
        const int rb = wn + s * 16 + ln;
        bfr[s] = *(const bf16x8*)(sB + rb * 128 + (((ks * 4 + lg) ^ (rb & 7)) << 4));
      }
#pragma unroll
      for (int s = 0; s < 4; ++s)
#pragma unroll
        for (int t = 0; t < 4; ++t)
          acc[s][t] = __builtin_amdgcn_mfma_f32_16x16x32_bf16(af[s], bfr[t], acc[s][t], 0, 0, 0);
    }
    __syncthreads();
  }
}

// ---------------- kernel A: kv = x @ w_kv^T + b, split k / v^T ----------------
// 1D grid 780 blocks, bijective XCD chunking. Epilogue: LDS-transpose then
// fully-coalesced 16B stores (1032 % 8 == 0 -> no chunk straddles a batch
// boundary or MTOT; every 16B chunk is wholly valid or wholly dropped).
__global__ __launch_bounds__(256) void kv_gemm(
    const u16* __restrict__ xb, const u16* __restrict__ wkvb,
    const float* __restrict__ bqkv, u16* __restrict__ khead, u16* __restrict__ vT) {
  __shared__ __align__(16) char smem[34816];   // mainloop 32KB; epilogue T 34KB
  char* sA = smem;
  char* sB = smem + 16384;
  const int bid = blockIdx.x;                 // 780 = 8*97 + 4
  const int xcd = bid & 7, loc = bid >> 3;
  const int wgid = (xcd < 4) ? xcd * 98 + loc : 392 + (xcd - 4) * 97 + loc;
  const int m0 = (wgid / 12) * 128, n0 = (wgid % 12) * 128;
  f32x4 acc[4][4] = {};
  gemm_mainloop(xb, wkvb, m0, n0, sA, sB, acc);
  const int tid = threadIdx.x, lane = tid & 63, w = tid >> 6;
  const int ln = lane & 15, lg = lane >> 4;
  const int wm = (w >> 1) * 64, wn = (w & 1) * 64;
  const bool isV = (n0 >= Cn);
  u16* T = (u16*)smem;                        // [128][136] u16 (272B rows, 16B-aligned)
  __syncthreads();                            // mainloop LDS reads done
  if (!isV) {
#pragma unroll
    for (int t = 0; t < 4; ++t) {
      const int c = wn + t * 16 + ln;
      const float bias = bqkv[Cn + n0 + c];
#pragma unroll
      for (int s = 0; s < 4; ++s)
#pragma unroll
        for (int r = 0; r < 4; ++r)
          T[(wm + s * 16 + lg * 4 + r) * 136 + c] = f2bf(acc[s][t][r] + bias);
    }
    __syncthreads();
    const int h0 = n0 >> 6;
#pragma unroll
    for (int i = 0; i < 8; ++i) {
      const int runid = w * 64 + i * 8 + (lane >> 3);
      const int mloc = runid >> 1, hh = runid & 1;
      const int m = m0 + mloc;
      if (m < MTOT) {
        const int b = m / Nn, nr = m - b * Nn;
        const int d0 = (lane & 7) * 8;
        *(uint4*)&khead[((size_t)(b * Hn + h0 + hh) * NQPc + nr) * HDn + d0] =
            *(const uint4*)&T[mloc * 136 + hh * 64 + d0];
      }
    }
  } else {
#pragma unroll
    for (int t = 0; t < 4; ++t) {
      const int c = wn + t * 16 + ln;
      const float bias = bqkv[Cn + n0 + c];
#pragma unroll
      for (int s = 0; s < 4; ++s)
#pragma unroll
        for (int r = 0; r < 4; ++r)
          T[c * 136 + wm + s * 16 + lg * 4 + r] = f2bf(acc[s][t][r] + bias);
    }
    __syncthreads();
    const int vch0 = n0 - Cn;
#pragma unroll
    for (int i = 0; i < 8; ++i) {
      const int c = w * 32 + i * 4 + lg;
      const int vch = vch0 + c, h = vch >> 6, d = vch & 63;
      const int m = m0 + ln * 8;
      if (m < MTOT) {
        const int b = m / Nn, nr = m - b * Nn;
        *(uint4*)&vT[((size_t)(b * Hn + h) * HDn + d) * NVM + nr] =
            *(const uint4*)&T[c * 136 + ln * 8];
      }
    }
  }
}

// ---------------- kernel B: fused gauss attention --------------------------
// 768 patch blocks (8 XCD * 96 = 12 bh * 8 qt of 128 patch-q; 3.0/CU exact) +
// 96 prefix blocks (XCD-affine: bh = (i&7)*12 + i>>3) as tail.
// Swapped QK^T; gauss in registers; sP qg-split; den via MFMA ones;
// double-buffered glds16 staging with counted vmcnt (R12 structure).
__global__ __launch_bounds__(256, 4) void attn_kernel(
    const u16* __restrict__ khead, const u16* __restrict__ vT, u16* __restrict__ attn) {
  __shared__ __align__(16) char sK[2][8192];
  __shared__ __align__(16) char sV[2][8192];
  __shared__ __align__(16) char sP[4][2048];   // per-wave [16 q][64 m] bf16, XOR-swz
  const int tid = threadIdx.x, lane = tid & 63, w = tid >> 6;
  const int ln = lane & 15, lg = lane >> 4;
  const int bid = blockIdx.x;

  bf16x8 ones8;
#pragma unroll
  for (int i = 0; i < 8; ++i) ones8[i] = (__bf16)1.0f;

  if (bid < 768) {
    // ================= patch block: 128 patch-q rows ======================
    const int xcd = bid & 7, loc = bid >> 3;
    const int lid = xcd * 96 + loc;            // 96/XCD = 12 bh * 8 qt
    const int qt = lid & 7, bh = lid >> 3;
    const int qb = PFXc + qt * 128 + w * 32;   // all q valid patch rows

    bf16x8 qf[2][2];
#pragma unroll
    for (int qg = 0; qg < 2; ++qg) {
      const char* qp = (const char*)(khead + ((size_t)bh * NQPc + qb + qg * 16 + ln) * HDn);
#pragma unroll
      for (int kc = 0; kc < 2; ++kc)
        qf[qg][kc] = *(const bf16x8*)(qp + kc * 64 + lg * 16);
    }

    // ---- per-lane gauss state, one set per q-group (registers only) ----
    const float c2 = EXP2(-2.0f * K2c);
    float ajr[2][8];
    float a0[2], a1[2], a2[2], fr[2];
#pragma unroll
    for (int qg = 0; qg < 2; ++qg) {
      const int pq = qt * 128 + w * 32 + qg * 16 + ln;   // 0..1023
      const int iq = pq >> 5, jq = pq & 31;
#pragma unroll
      for (int t = 0; t < 8; ++t) {
        const int jm = (lg * 4 - 8 + (t >> 2) * 16 + (t & 3)) & 31;
        const float d = (float)(jq - jm);
        ajr[qg][t] = EXP2(-d * d * K2c);
      }
      const float d1 = (float)(iq + 1), d0 = (float)iq, dm = (float)(iq - 1);
      a0[qg] = EXP2(-d1 * d1 * K2c) * LOG2Ec;
      a1[qg] = EXP2(-d0 * d0 * K2c) * LOG2Ec;
      a2[qg] = EXP2(-dm * dm * K2c) * LOG2Ec;
      fr[qg] = EXP2((2.0f * (float)iq - 3.0f) * K2c);
    }

    const char* ksrc = (const char*)(khead + (size_t)bh * NQPc * HDn);
    const char* vsrc = (const char*)(vT + (size_t)bh * HDn * NVM);

#define STAGE(buf, mb) do { \
  _Pragma("unroll") for (int i_ = 0; i_ < 2; ++i_) { \
    const int c_ = i_ * 256 + tid, r_ = c_ >> 3, gcb_ = (c_ & 7) ^ (r_ & 7); \
    glds16(ksrc + (size_t)((mb) + r_) * 128 + gcb_ * 16, sK[buf] + i_ * 4096 + w * 1024); \
    glds16(vsrc + (size_t)r_ * (NVM * 2) + (mb) * 2 + gcb_ * 16, sV[buf] + i_ * 4096 + w * 1024); \
  } } while (0)

    f32x4 oacc[4][2] = {};
    f32x4 dacc[2] = {};
    STAGE(0, 0);                        // 4 glds in flight; first iter waits

    for (int mc = 0; mc < 17; ++mc) {
      const int cur = mc & 1;
      const int mb = mc * 64;
      if (mc < 16) {
        STAGE(cur ^ 1, mb + 64);        // +4 glds -> up to 8 outstanding
        asm volatile("s_waitcnt vmcnt(4)" ::: "memory");
      } else {
        asm volatile("s_waitcnt vmcnt(0)" ::: "memory");
      }
      __builtin_amdgcn_sched_barrier(0);
      __builtin_amdgcn_s_barrier();     // all waves: cur tile ready
      __builtin_amdgcn_sched_barrier(0);

      // S^T = K Q : rows = m (lg*4+reg), cols = q (ln); kf shared by both qg
      f32x4 sacc[4][2] = {};
      __builtin_amdgcn_s_setprio(1);
#pragma unroll
      for (int ms = 0; ms < 4; ++ms) {
        const int r = ms * 16 + ln;
#pragma unroll
        for (int kc = 0; kc < 2; ++kc) {
          bf16x8 kf = *(const bf16x8*)(sK[cur] + r * 128 + (((kc * 4 + lg) ^ (r & 7)) << 4));
          sacc[ms][0] = __builtin_amdgcn_mfma_f32_16x16x32_bf16(kf, qf[0][kc], sacc[ms][0], 0, 0, 0);
          sacc[ms][1] = __builtin_amdgcn_mfma_f32_16x16x32_bf16(kf, qf[1][kc], sacc[ms][1], 0, 0, 0);
        }
      }
      __builtin_amdgcn_s_setprio(0);

      // P = exp2(S*c1 + al*ajr); qg-split through 2 KB sP (wave-local).
      // mc==0: zero gauss for prefix m<8; mc==16: zero for pad m>=1032 -> p=1.
      bf16x8 pf[2][2];
#pragma unroll
      for (int qg = 0; qg < 2; ++qg) {
        const float b0 = (mc == 0) ? 0.f : a0[qg];
        const float b1 = (mc == 16) ? 0.f : a1[qg];
        const float b2 = (mc == 16) ? 0.f : a2[qg];
#pragma unroll
        for (int ms = 0; ms < 4; ++ms) {
          float al;
          if (ms == 0)      al = (lg < 2) ? b0 : b1;
          else if (ms == 1) al = b1;
          else if (ms == 2) al = (lg < 2) ? b1 : b2;
          else              al = b2;
          const int t0 = (ms & 1) * 4;
          const float p0 = EXP2(fmaf(sacc[ms][qg][0], C1c, al * ajr[qg][t0 + 0]));
          const float p1 = EXP2(fmaf(sacc[ms][qg][1], C1c, al * ajr[qg][t0 + 1]));
          const float p2 = EXP2(fmaf(sacc[ms][qg][2], C1c, al * ajr[qg][t0 + 2]));
          const float p3 = EXP2(fmaf(sacc[ms][qg][3], C1c, al * ajr[qg][t0 + 3]));
          bf16x4 pk;
          pk[0] = (__bf16)p0; pk[1] = (__bf16)p1; pk[2] = (__bf16)p2; pk[3] = (__bf16)p3;
          *(bf16x4*)(sP[w] + ln * 128 + ((ms * 32 + lg * 8) ^ ((ln & 7) << 4))) = pk;
        }
#pragma unroll
        for (int km = 0; km < 2; ++km)
          pf[qg][km] = *(const bf16x8*)(sP[w] + ln * 128 +
                                        ((km * 64 + lg * 16) ^ ((ln & 7) << 4)));
        // advance this qg's al window by 2 m-groups (im += 2)
        a0[qg] = a2[qg];
        a1[qg] = a2[qg] * fr[qg]; fr[qg] *= c2;
        a2[qg] = a1[qg] * fr[qg]; fr[qg] *= c2;
      }

      // O += P V; den += P * ones. vf shared by both qg.
      __builtin_amdgcn_s_setprio(1);
      dacc[0] = __builtin_amdgcn_mfma_f32_16x16x32_bf16(pf[0][0], ones8, dacc[0], 0, 0, 0);
      dacc[0] = __builtin_amdgcn_mfma_f32_16x16x32_bf16(pf[0][1], ones8, dacc[0], 0, 0, 0);
      dacc[1] = __builtin_amdgcn_mfma_f32_16x16x32_bf16(pf[1][0], ones8, dacc[1], 0, 0, 0);
      dacc[1] = __builtin_amdgcn_mfma_f32_16x16x32_bf16(pf[1][1], ones8, dacc[1], 0, 0, 0);
#pragma unroll
      for (int ds = 0; ds < 4; ++ds) {
        const int r = ds * 16 + ln;
#pragma unroll
        for (int km = 0; km < 2; ++km) {
          bf16x8 vf = *(const bf16x8*)(sV[cur] + r * 128 + (((km * 4 + lg) ^ (r & 7)) << 4));
          oacc[ds][0] = __builtin_amdgcn_mfma_f32_16x16x32_bf16(pf[0][km], vf, oacc[ds][0], 0, 0, 0);
          oacc[ds][1] = __builtin_amdgcn_mfma_f32_16x16x32_bf16(pf[1][km], vf, oacc[ds][1], 0, 0, 0);
        }
      }
      __builtin_amdgcn_s_setprio(0);
      __builtin_amdgcn_sched_barrier(0);
      __builtin_amdgcn_s_barrier();     // all waves done with cur before overwrite
      __builtin_amdgcn_sched_barrier(0);
    }
#undef STAGE

    // dacc[qg][r] = den for q = qb + qg*16 + lg*4 + r (replicated across ln)
    const int b = bh / Hn, h = bh - b * Hn;
#pragma unroll
    for (int qg = 0; qg < 2; ++qg) {
#pragma unroll
      for (int r = 0; r < 4; ++r) {
        const int qo = qb + qg * 16 + lg * 4 + r;   // always < Nn
        const float dinv = 1.0f / (dacc[qg][r] - (float)NPADQ);
#pragma unroll
        for (int ds = 0; ds < 4; ++ds)
          attn[((size_t)(b * Nn + qo)) * Cn + h * HDn + ds * 16 + ln] =
              f2bf(oacc[ds][qg][r] * dinv);
      }
    }
  } else {
    // ================= prefix block: 8 real q rows, m-split over waves ====
    const int i = bid - 768;
    const int bh = (i & 7) * 12 + (i >> 3);    // XCD-affine with patch blocks
    const char* ksrc = (const char*)(khead + (size_t)bh * NQPc * HDn);
    const char* vsrc = (const char*)(vT + (size_t)bh * HDn * NVM);
    const char* qp = (const char*)(khead + ((size_t)bh * NQPc + ln) * HDn);
    bf16x8 qf[2];
    qf[0] = *(const bf16x8*)(qp + lg * 16);
    qf[1] = *(const bf16x8*)(qp + 64 + lg * 16);

    f32x4 oacc[4] = {};
    f32x4 dacc = {};
    for (int mc = w; mc < 17; mc += 4) {       // wave-strided m tiles, no barriers
      const int mb = mc * 64;
      f32x4 sacc[4] = {};
#pragma unroll
      for (int ms = 0; ms < 4; ++ms) {
        const char* kp = ksrc + (size_t)(mb + ms * 16 + ln) * 128 + lg * 16;
        bf16x8 kf0 = *(const bf16x8*)(kp);
        bf16x8 kf1 = *(const bf16x8*)(kp + 64);
        sacc[ms] = __builtin_amdgcn_mfma_f32_16x16x32_bf16(kf0, qf[0], sacc[ms], 0, 0, 0);
        sacc[ms] = __builtin_amdgcn_mfma_f32_16x16x32_bf16(kf1, qf[1], sacc[ms], 0, 0, 0);
      }
      // P = exp2(S*c1): no gauss for prefix q (add rows are zero)
#pragma unroll
      for (int ms = 0; ms < 4; ++ms) {
        bf16x4 pk;
        pk[0] = (__bf16)EXP2(sacc[ms][0] * C1c);
        pk[1] = (__bf16)EXP2(sacc[ms][1] * C1c);
        pk[2] = (__bf16)EXP2(sacc[ms][2] * C1c);
        pk[3] = (__bf16)EXP2(sacc[ms][3] * C1c);
        *(bf16x4*)(sP[w] + ln * 128 + ((ms * 32 + lg * 8) ^ ((ln & 7) << 4))) = pk;
      }
      bf16x8 pf[2];
#pragma unroll
      for (int km = 0; km < 2; ++km)
        pf[km] = *(const bf16x8*)(sP[w] + ln * 128 + ((km * 64 + lg * 16) ^ ((ln & 7) << 4)));
      dacc = __builtin_amdgcn_mfma_f32_16x16x32_bf16(pf[0], ones8, dacc, 0, 0, 0);
      dacc = __builtin_amdgcn_mfma_f32_16x16x32_bf16(pf[1], ones8, dacc, 0, 0, 0);
#pragma unroll
      for (int ds = 0; ds < 4; ++ds) {
        const char* vp = vsrc + (size_t)(ds * 16 + ln) * (NVM * 2) + mb * 2 + lg * 16;
#pragma unroll
        for (int km = 0; km < 2; ++km) {
          bf16x8 vf = *(const bf16x8*)(vp + km * 64);
          oacc[ds] = __builtin_amdgcn_mfma_f32_16x16x32_bf16(pf[km], vf, oacc[ds], 0, 0, 0);
        }
      }
    }
    // merge partials across waves via LDS (sK: 16KB oacc, sV: 4KB dacc)
    char* sKf = (char*)sK;
    char* sVf = (char*)sV;
    __syncthreads();
#pragma unroll
    for (int ds = 0; ds < 4; ++ds)
      *(f32x4*)(sKf + (((w * 4 + ds) * 64 + lane) << 4)) = oacc[ds];
    *(f32x4*)(sVf + ((w * 64 + lane) << 4)) = dacc;
    __syncthreads();
    f32x4 osum = {}, dsum = {};
#pragma unroll
    for (int wp = 0; wp < 4; ++wp) {
      osum += *(const f32x4*)(sKf + (((wp * 4 + w) * 64 + lane) << 4));
      dsum += *(const f32x4*)(sVf + ((wp * 64 + lane) << 4));
    }
    const int b = bh / Hn, h = bh - b * Hn;
#pragma unroll
    for (int r = 0; r < 4; ++r) {
      const int q = lg * 4 + r;
      if (q < PFXc)
        attn[((size_t)(b * Nn + q)) * Cn + h * HDn + w * 16 + ln] =
            f2bf(osum[r] / (dsum[r] - (float)NPADQ));
    }
  }
}

// ---------------- kernel C: out = attn @ w_proj^T + b_proj ----------------
// 1D grid 390 blocks, bijective XCD chunking
__global__ __launch_bounds__(256) void proj_gemm(
    const u16* __restrict__ at, const u16* __restrict__ wpb,
    const float* __restrict__ bproj, float* __restrict__ out) {
  __shared__ __align__(16) char sA[16384];
  __shared__ __align__(16) char sB[16384];
  const int bid = blockIdx.x;                 // 390 = 8*48 + 6
  const int xcd = bid & 7, loc = bid >> 3;
  const int wgid = (xcd < 6) ? xcd * 49 + loc : 294 + (xcd - 6) * 48 + loc;
  const int m0 = (wgid / 6) * 128, n0 = (wgid % 6) * 128;
  f32x4 acc[4][4] = {};
  gemm_mainloop(at, wpb, m0, n0, sA, sB, acc);
  const int tid = threadIdx.x, lane = tid & 63, w = tid >> 6;
  const int ln = lane & 15, lg = lane >> 4;
  const int wm = (w >> 1) * 64, wn = (w & 1) * 64;
#pragma unroll
  for (int t = 0; t < 4; ++t) {
    const int n = n0 + wn + t * 16 + ln;
    const float bias = bproj[n];
#pragma unroll
    for (int s = 0; s < 4; ++s) {
#pragma unroll
      for (int r = 0; r < 4; ++r) {
        const int m = m0 + wm + s * 16 + lg * 4 + r;
        if (m < MTOT) out[(size_t)m * Cn + n] = acc[s][t][r] + bias;
      }
    }
  }
}

extern "C" void kernel_launch(void* const* d_in, const int* in_sizes, int n_in,
                              void* d_out, int out_size, void* d_ws, size_t ws_size,
                              hipStream_t stream) {
  const float* x     = (const float*)d_in[0];
  const float* wqkv  = (const float*)d_in[1];
  const float* bqkv  = (const float*)d_in[2];
  const float* wproj = (const float*)d_in[3];
  const float* bproj = (const float*)d_in[4];
  char* ws = (char*)d_ws;
  u16* xb    = (u16*)(ws + OFF_XB);
  u16* wkvb  = (u16*)(ws + OFF_WKV);
  u16* wpb   = (u16*)(ws + OFF_WP);
  u16* khead = (u16*)(ws + OFF_K);
  u16* vT    = (u16*)(ws + OFF_V);
  u16* attn  = (u16*)(ws + OFF_AT);    // aliases xb (xb dead by then)

  prep_kernel<<<2048, 256, 0, stream>>>(x, wqkv, wproj, xb, wkvb, wpb, khead, vT);
  kv_gemm<<<780, 256, 0, stream>>>(xb, wkvb, bqkv, khead, vT);
  attn_kernel<<<864, 256, 0, stream>>>(khead, vT, attn);
  proj_gemm<<<390, 256, 0, stream>>>(attn, wpb, bproj, (float*)d_out);
}

// Round 15
// 119.487 us; speedup vs baseline: 1.4470x; 1.0342x over previous
//
#include <hip/hip_runtime.h>
#include <hip/hip_bf16.h>

typedef unsigned short u16;
typedef __bf16 bf16x8 __attribute__((ext_vector_type(8)));
typedef __bf16 bf16x4 __attribute__((ext_vector_type(4)));
typedef float f32x4 __attribute__((ext_vector_type(4)));

#define DEVI __device__ __forceinline__

#if __has_builtin(__builtin_amdgcn_exp2f)
#define EXP2 __builtin_amdgcn_exp2f    // raw v_exp_f32 (args are in [-12,10]: safe)
#else
#define EXP2 exp2f
#endif

// ---- problem constants ----
constexpr int Bn = 8, Nn = 1032, Cn = 768, Hn = 12, HDn = 64;
constexpr int NQPc = 1088;             // khead rows per bh (17 * 64; serves q and m)
constexpr int NVM = 1088;              // m extent (17 m-tiles * 64)
constexpr int MTOT = Bn * Nn;          // 8256
constexpr int MPAD = 8320;             // 65 * 128
constexpr int KVN = 1536;
constexpr int PFXc = 8;
constexpr int NPADQ = NVM - Nn;        // 56 zero-padded m positions
constexpr float SCALEc = 0.125f;
constexpr float LOG2Ec = 1.4426950408889634f;
constexpr float C1c = SCALEc * LOG2Ec;
constexpr float INV2S2c = 0.02f;
constexpr float K2c = INV2S2c * LOG2Ec;   // gauss exponent scale in exp2 domain

// ---- workspace layout (attn output aliases xb: xb dead before attn writes) ----
constexpr size_t OFF_XB  = 0;
constexpr size_t SZ_XB   = (size_t)MPAD * Cn * 2;             // 12.78 MB
constexpr size_t OFF_AT  = OFF_XB;                            // alias
constexpr size_t OFF_WKV = OFF_XB + SZ_XB;
constexpr size_t SZ_WKV  = (size_t)KVN * Cn * 2;
constexpr size_t OFF_WP  = OFF_WKV + SZ_WKV;
constexpr size_t SZ_WP   = (size_t)Cn * Cn * 2;
constexpr size_t OFF_K   = OFF_WP + SZ_WP;
constexpr size_t SZ_K    = (size_t)Bn * Hn * NQPc * HDn * 2;  // 13.4 MB
constexpr size_t OFF_V   = OFF_K + SZ_K;
constexpr size_t SZ_V    = (size_t)Bn * Hn * HDn * NVM * 2;   // 13.4 MB

DEVI u16 f2bf(float f) {
  __bf16 h = (__bf16)f;                 // hardware cvt, RNE
  return *reinterpret_cast<u16*>(&h);
}

DEVI void glds16(const void* g, void* l) {
  __builtin_amdgcn_global_load_lds((const __attribute__((address_space(1))) void*)g,
                                   (__attribute__((address_space(3))) void*)l, 16, 0, 0);
}

// ---------------- prep: fp32->bf16 + zero pad regions ----------------
__global__ __launch_bounds__(256) void prep_kernel(
    const float* __restrict__ x, const float* __restrict__ wqkv,
    const float* __restrict__ wproj, u16* __restrict__ xb,
    u16* __restrict__ wkvb, u16* __restrict__ wpb,
    u16* __restrict__ khead, u16* __restrict__ vT) {
  const int n1 = MPAD * Cn / 4, n2 = KVN * Cn / 4, n3 = Cn * Cn / 4;
  const int z1 = 96 * 448;             // khead pad rows: 96 bh * 56 rows * 128B/16B
  const int z2 = 6144 * 7;             // vT pad cols
  const int nc = n1 + n2 + n3;
  const int tot = nc + z1 + z2;
  for (int i = blockIdx.x * blockDim.x + threadIdx.x; i < tot; i += gridDim.x * blockDim.x) {
    if (i < nc) {
      const float* src; u16* dst;
      if (i < n1) {
        int e = i * 4;
        src = (e < MTOT * Cn) ? (x + e) : nullptr;
        dst = xb + e;
      } else if (i < n1 + n2) {
        int e = (i - n1) * 4;
        src = wqkv + Cn * Cn + e;               // skip q-weights (q unused)
        dst = wkvb + e;
      } else {
        int e = (i - n1 - n2) * 4;
        src = wproj + e;
        dst = wpb + e;
      }
      float4 f = src ? *(const float4*)src : make_float4(0.f, 0.f, 0.f, 0.f);
      *(ushort4*)dst = make_ushort4(f2bf(f.x), f2bf(f.y), f2bf(f.z), f2bf(f.w));
    } else if (i < nc + z1) {
      int j = i - nc, bh = j / 448, c = j - bh * 448;
      char* dst = (char*)khead + ((size_t)bh * NQPc + Nn) * HDn * 2 + c * 16;
      *(ushort4*)dst = make_ushort4(0, 0, 0, 0);
      *(ushort4*)(dst + 8) = make_ushort4(0, 0, 0, 0);
    } else {
      int j = i - nc - z1, st = j / 7, c = j - st * 7;
      char* dst = (char*)vT + ((size_t)st * NVM + Nn) * 2 + c * 16;
      *(ushort4*)dst = make_ushort4(0, 0, 0, 0);
      *(ushort4*)(dst + 8) = make_ushort4(0, 0, 0, 0);
    }
  }
}

// ---------------- shared 128x128 BK=64 bt-GEMM mainloop (R9 form) -------------
DEVI void gemm_mainloop(const u16* __restrict__ A, const u16* __restrict__ Bm,
                        int m0, int n0, char* sA, char* sB, f32x4 (&acc)[4][4]) {
  const int tid = threadIdx.x, lane = tid & 63, w = tid >> 6;
  const int ln = lane & 15, lg = lane >> 4;
  const int wm = (w >> 1) * 64, wn = (w & 1) * 64;
  for (int kt = 0; kt < 12; ++kt) {
#pragma unroll
    for (int i = 0; i < 4; ++i) {
      const int c = i * 256 + tid, r = c >> 3, cb = c & 7, gcb = cb ^ (r & 7);
      const char* ga = (const char*)(A + (size_t)(m0 + r) * Cn + kt * 64) + gcb * 16;
      glds16(ga, sA + i * 4096 + w * 1024);
      const char* gb = (const char*)(Bm + (size_t)(n0 + r) * Cn + kt * 64) + gcb * 16;
      glds16(gb, sB + i * 4096 + w * 1024);
    }
    __syncthreads();
#pragma unroll
    for (int ks = 0; ks < 2; ++ks) {
      bf16x8 af[4], bfr[4];
#pragma unroll
      for (int s = 0; s < 4; ++s) {
        const int ra = wm + s * 16 + ln;
        af[s] = *(const bf16x8*)(sA + ra * 128 + (((ks * 4 + lg) ^ (ra & 7)) << 4));
        const int rb = wn + s * 16 + ln;
        bfr[s] = *(const bf16x8*)(sB + rb * 128 + (((ks * 4 + lg) ^ (rb & 7)) << 4));
      }
#pragma unroll
      for (int s = 0; s < 4; ++s)
#pragma unroll
        for (int t = 0; t < 4; ++t)
          acc[s][t] = __builtin_amdgcn_mfma_f32_16x16x32_bf16(af[s], bfr[t], acc[s][t], 0, 0, 0);
    }
    __syncthreads();
  }
}

// ---------------- kernel A: kv = x @ w_kv^T + b, split k / v^T ----------------
// 1D grid 780 blocks, bijective XCD chunking. Epilogue: LDS-transpose then
// fully-coalesced 16B stores (1032 % 8 == 0 -> no chunk straddles a batch
// boundary or MTOT; every 16B chunk is wholly valid or wholly dropped).
__global__ __launch_bounds__(256) void kv_gemm(
    const u16* __restrict__ xb, const u16* __restrict__ wkvb,
    const float* __restrict__ bqkv, u16* __restrict__ khead, u16* __restrict__ vT) {
  __shared__ __align__(16) char smem[34816];   // mainloop 32KB; epilogue T 34KB
  char* sA = smem;
  char* sB = smem + 16384;
  const int bid = blockIdx.x;                 // 780 = 8*97 + 4
  const int xcd = bid & 7, loc = bid >> 3;
  const int wgid = (xcd < 4) ? xcd * 98 + loc : 392 + (xcd - 4) * 97 + loc;
  const int m0 = (wgid / 12) * 128, n0 = (wgid % 12) * 128;
  f32x4 acc[4][4] = {};
  gemm_mainloop(xb, wkvb, m0, n0, sA, sB, acc);
  const int tid = threadIdx.x, lane = tid & 63, w = tid >> 6;
  const int ln = lane & 15, lg = lane >> 4;
  const int wm = (w >> 1) * 64, wn = (w & 1) * 64;
  const bool isV = (n0 >= Cn);
  u16* T = (u16*)smem;                        // [128][136] u16 (272B rows, 16B-aligned)
  __syncthreads();                            // mainloop LDS reads done
  if (!isV) {
#pragma unroll
    for (int t = 0; t < 4; ++t) {
      const int c = wn + t * 16 + ln;
      const float bias = bqkv[Cn + n0 + c];
#pragma unroll
      for (int s = 0; s < 4; ++s)
#pragma unroll
        for (int r = 0; r < 4; ++r)
          T[(wm + s * 16 + lg * 4 + r) * 136 + c] = f2bf(acc[s][t][r] + bias);
    }
    __syncthreads();
    const int h0 = n0 >> 6;
#pragma unroll
    for (int i = 0; i < 8; ++i) {
      const int runid = w * 64 + i * 8 + (lane >> 3);
      const int mloc = runid >> 1, hh = runid & 1;
      const int m = m0 + mloc;
      if (m < MTOT) {
        const int b = m / Nn, nr = m - b * Nn;
        const int d0 = (lane & 7) * 8;
        *(uint4*)&khead[((size_t)(b * Hn + h0 + hh) * NQPc + nr) * HDn + d0] =
            *(const uint4*)&T[mloc * 136 + hh * 64 + d0];
      }
    }
  } else {
#pragma unroll
    for (int t = 0; t < 4; ++t) {
      const int c = wn + t * 16 + ln;
      const float bias = bqkv[Cn + n0 + c];
#pragma unroll
      for (int s = 0; s < 4; ++s)
#pragma unroll
        for (int r = 0; r < 4; ++r)
          T[c * 136 + wm + s * 16 + lg * 4 + r] = f2bf(acc[s][t][r] + bias);
    }
    __syncthreads();
    const int vch0 = n0 - Cn;
#pragma unroll
    for (int i = 0; i < 8; ++i) {
      const int c = w * 32 + i * 4 + lg;
      const int vch = vch0 + c, h = vch >> 6, d = vch & 63;
      const int m = m0 + ln * 8;
      if (m < MTOT) {
        const int b = m / Nn, nr = m - b * Nn;
        *(uint4*)&vT[((size_t)(b * Hn + h) * HDn + d) * NVM + nr] =
            *(const uint4*)&T[c * 136 + ln * 8];
      }
    }
  }
}

// ---------------- kernel B: fused gauss attention --------------------------
// 768 patch blocks + 96 XCD-affine prefix blocks. Patch: software-pipelined:
// QK^T(mc+1) [MFMA] interleaves with P(mc) [VALU exp2] in one sched region;
// K staged 2 ahead, V 1 ahead, counted vmcnt(4); sacc double-banked (A/B,
// manual unroll-by-2 for static indexing).
__global__ __launch_bounds__(256) void attn_kernel(
    const u16* __restrict__ khead, const u16* __restrict__ vT, u16* __restrict__ attn) {
  __shared__ __align__(16) char sK[2][8192];
  __shared__ __align__(16) char sV[2][8192];
  __shared__ __align__(16) char sP[4][2048];   // per-wave [16 q][64 m] bf16, XOR-swz
  const int tid = threadIdx.x, lane = tid & 63, w = tid >> 6;
  const int ln = lane & 15, lg = lane >> 4;
  const int bid = blockIdx.x;

  bf16x8 ones8;
#pragma unroll
  for (int i = 0; i < 8; ++i) ones8[i] = (__bf16)1.0f;
  const f32x4 fzero = {0.f, 0.f, 0.f, 0.f};

  if (bid < 768) {
    // ================= patch block: 128 patch-q rows ======================
    const int xcd = bid & 7, loc = bid >> 3;
    const int lid = xcd * 96 + loc;            // 96/XCD = 12 bh * 8 qt
    const int qt = lid & 7, bh = lid >> 3;
    const int qb = PFXc + qt * 128 + w * 32;   // all q valid patch rows

    bf16x8 qf[2][2];
#pragma unroll
    for (int qg = 0; qg < 2; ++qg) {
      const char* qp = (const char*)(khead + ((size_t)bh * NQPc + qb + qg * 16 + ln) * HDn);
#pragma unroll
      for (int kc = 0; kc < 2; ++kc)
        qf[qg][kc] = *(const bf16x8*)(qp + kc * 64 + lg * 16);
    }

    // ---- per-lane gauss state, one set per q-group (registers only) ----
    const float c2 = EXP2(-2.0f * K2c);
    float ajr[2][8];
    float a0[2], a1[2], a2[2], fr[2];
#pragma unroll
    for (int qg = 0; qg < 2; ++qg) {
      const int pq = qt * 128 + w * 32 + qg * 16 + ln;   // 0..1023
      const int iq = pq >> 5, jq = pq & 31;
#pragma unroll
      for (int t = 0; t < 8; ++t) {
        const int jm = (lg * 4 - 8 + (t >> 2) * 16 + (t & 3)) & 31;
        const float d = (float)(jq - jm);
        ajr[qg][t] = EXP2(-d * d * K2c);
      }
      const float d1 = (float)(iq + 1), d0 = (float)iq, dm = (float)(iq - 1);
      a0[qg] = EXP2(-d1 * d1 * K2c) * LOG2Ec;
      a1[qg] = EXP2(-d0 * d0 * K2c) * LOG2Ec;
      a2[qg] = EXP2(-dm * dm * K2c) * LOG2Ec;
      fr[qg] = EXP2((2.0f * (float)iq - 3.0f) * K2c);
    }

    const char* ksrc = (const char*)(khead + (size_t)bh * NQPc * HDn);
    const char* vsrc = (const char*)(vT + (size_t)bh * HDn * NVM);

#define STAGE_K(buf, mb) do { \
  _Pragma("unroll") for (int i_ = 0; i_ < 2; ++i_) { \
    const int c_ = i_ * 256 + tid, r_ = c_ >> 3, gcb_ = (c_ & 7) ^ (r_ & 7); \
    glds16(ksrc + (size_t)((mb) + r_) * 128 + gcb_ * 16, sK[buf] + i_ * 4096 + w * 1024); \
  } } while (0)
#define STAGE_V(buf, mb) do { \
  _Pragma("unroll") for (int i_ = 0; i_ < 2; ++i_) { \
    const int c_ = i_ * 256 + tid, r_ = c_ >> 3, gcb_ = (c_ & 7) ^ (r_ & 7); \
    glds16(vsrc + (size_t)r_ * (NVM * 2) + (mb) * 2 + gcb_ * 16, sV[buf] + i_ * 4096 + w * 1024); \
  } } while (0)
#define QK_STEP(kb, SACC) do { \
  _Pragma("unroll") \
  for (int z_ = 0; z_ < 4; ++z_) { SACC[z_][0] = fzero; SACC[z_][1] = fzero; } \
  __builtin_amdgcn_s_setprio(1); \
  _Pragma("unroll") \
  for (int ms_ = 0; ms_ < 4; ++ms_) { \
    const int r_ = ms_ * 16 + ln; \
    _Pragma("unroll") \
    for (int kc_ = 0; kc_ < 2; ++kc_) { \
      bf16x8 kf_ = *(const bf16x8*)(sK[kb] + r_ * 128 + (((kc_ * 4 + lg) ^ (r_ & 7)) << 4)); \
      SACC[ms_][0] = __builtin_amdgcn_mfma_f32_16x16x32_bf16(kf_, qf[0][kc_], SACC[ms_][0], 0, 0, 0); \
      SACC[ms_][1] = __builtin_amdgcn_mfma_f32_16x16x32_bf16(kf_, qf[1][kc_], SACC[ms_][1], 0, 0, 0); \
    } } \
  __builtin_amdgcn_s_setprio(0); } while (0)
#define P_PHASE(SACC, is0v, is16v) do { \
  _Pragma("unroll") \
  for (int qg_ = 0; qg_ < 2; ++qg_) { \
    const float b0_ = (is0v) ? 0.f : a0[qg_]; \
    const float b1_ = (is16v) ? 0.f : a1[qg_]; \
    const float b2_ = (is16v) ? 0.f : a2[qg_]; \
    _Pragma("unroll") \
    for (int ms_ = 0; ms_ < 4; ++ms_) { \
      float al_; \
      if (ms_ == 0)      al_ = (lg < 2) ? b0_ : b1_; \
      else if (ms_ == 1) al_ = b1_; \
      else if (ms_ == 2) al_ = (lg < 2) ? b1_ : b2_; \
      else               al_ = b2_; \
      const int t0_ = (ms_ & 1) * 4; \
      const float p0_ = EXP2(fmaf(SACC[ms_][qg_][0], C1c, al_ * ajr[qg_][t0_ + 0])); \
      const float p1_ = EXP2(fmaf(SACC[ms_][qg_][1], C1c, al_ * ajr[qg_][t0_ + 1])); \
      const float p2_ = EXP2(fmaf(SACC[ms_][qg_][2], C1c, al_ * ajr[qg_][t0_ + 2])); \
      const float p3_ = EXP2(fmaf(SACC[ms_][qg_][3], C1c, al_ * ajr[qg_][t0_ + 3])); \
      bf16x4 pk_; \
      pk_[0] = (__bf16)p0_; pk_[1] = (__bf16)p1_; pk_[2] = (__bf16)p2_; pk_[3] = (__bf16)p3_; \
      *(bf16x4*)(sP[w] + ln * 128 + ((ms_ * 32 + lg * 8) ^ ((ln & 7) << 4))) = pk_; \
    } \
    _Pragma("unroll") \
    for (int km_ = 0; km_ < 2; ++km_) \
      pf[qg_][km_] = *(const bf16x8*)(sP[w] + ln * 128 + ((km_ * 64 + lg * 16) ^ ((ln & 7) << 4))); \
    a0[qg_] = a2[qg_]; \
    a1[qg_] = a2[qg_] * fr[qg_]; fr[qg_] *= c2; \
    a2[qg_] = a1[qg_] * fr[qg_]; fr[qg_] *= c2; \
  } } while (0)
#define PV_STEP(vb) do { \
  __builtin_amdgcn_s_setprio(1); \
  dacc[0] = __builtin_amdgcn_mfma_f32_16x16x32_bf16(pf[0][0], ones8, dacc[0], 0, 0, 0); \
  dacc[0] = __builtin_amdgcn_mfma_f32_16x16x32_bf16(pf[0][1], ones8, dacc[0], 0, 0, 0); \
  dacc[1] = __builtin_amdgcn_mfma_f32_16x16x32_bf16(pf[1][0], ones8, dacc[1], 0, 0, 0); \
  dacc[1] = __builtin_amdgcn_mfma_f32_16x16x32_bf16(pf[1][1], ones8, dacc[1], 0, 0, 0); \
  _Pragma("unroll") \
  for (int ds_ = 0; ds_ < 4; ++ds_) { \
    const int r_ = ds_ * 16 + ln; \
    _Pragma("unroll") \
    for (int km_ = 0; km_ < 2; ++km_) { \
      bf16x8 vf_ = *(const bf16x8*)(sV[vb] + r_ * 128 + (((km_ * 4 + lg) ^ (r_ & 7)) << 4)); \
      oacc[ds_][0] = __builtin_amdgcn_mfma_f32_16x16x32_bf16(pf[0][km_], vf_, oacc[ds_][0], 0, 0, 0); \
      oacc[ds_][1] = __builtin_amdgcn_mfma_f32_16x16x32_bf16(pf[1][km_], vf_, oacc[ds_][1], 0, 0, 0); \
    } } \
  __builtin_amdgcn_s_setprio(0); } while (0)
#define BARRIER() do { __builtin_amdgcn_sched_barrier(0); \
  __builtin_amdgcn_s_barrier(); __builtin_amdgcn_sched_barrier(0); } while (0)

    f32x4 saccA[4][2], saccB[4][2];
    f32x4 oacc[4][2] = {};
    f32x4 dacc[2] = {};
    bf16x8 pf[2][2];

    // prologue: K0, V0, K1 staged; QK(0) -> saccA
    STAGE_K(0, 0); STAGE_V(0, 0); STAGE_K(1, 64);        // 6 glds
    asm volatile("s_waitcnt vmcnt(4)" ::: "memory");     // K0 landed (V0,K1 fly)
    BARRIER();
    QK_STEP(0, saccA);

    for (int d = 0; d < 8; ++d) {
      // ---- even half: mc = 2d (consume saccA, produce saccB) ----
      BARRIER();                                 // all waves: QK(2d), PV(2d-1) done
      STAGE_K(0, (2 * d + 2) * 64);              // K(2d+2) -> sK[0] (K(2d) free)
      STAGE_V(1, (2 * d + 1) * 64);              // V(2d+1) -> sV[1] (V(2d-1) free)
      asm volatile("s_waitcnt vmcnt(4)" ::: "memory");   // K(2d+1), V(2d) landed
      BARRIER();                                 // and visible block-wide
      QK_STEP(1, saccB);                         // QK(2d+1)  [MFMA pipe]
      P_PHASE(saccA, (d == 0), false);           // P(2d)     [VALU pipe, overlaps]
      PV_STEP(0);                                // PV(2d) from sV[0]
      // ---- odd half: mc = 2d+1 (consume saccB, produce saccA) ----
      BARRIER();                                 // all waves: QK(2d+1), PV(2d) done
      if (d < 7) {
        STAGE_K(1, (2 * d + 3) * 64);            // K(2d+3) -> sK[1]
        STAGE_V(0, (2 * d + 2) * 64);            // V(2d+2) -> sV[0]
        asm volatile("s_waitcnt vmcnt(4)" ::: "memory"); // K(2d+2), V(2d+1) landed
      } else {
        STAGE_V(0, 16 * 64);                     // V(16) -> sV[0]
        asm volatile("s_waitcnt vmcnt(2)" ::: "memory"); // K(16), V(15) landed
      }
      BARRIER();
      QK_STEP(0, saccA);                         // QK(2d+2)
      P_PHASE(saccB, false, false);              // P(2d+1)
      PV_STEP(1);                                // PV(2d+1) from sV[1]
    }
    // ---- epilogue: mc = 16 (saccA holds QK(16)) ----
    asm volatile("s_waitcnt vmcnt(0)" ::: "memory");     // V(16) landed
    BARRIER();                                   // visible; all PV(15) done
    P_PHASE(saccA, false, true);
    PV_STEP(0);

#undef STAGE_K
#undef STAGE_V
#undef QK_STEP
#undef P_PHASE
#undef PV_STEP
#undef BARRIER

    // dacc[qg][r] = den for q = qb + qg*16 + lg*4 + r (replicated across ln)
    const int b = bh / Hn, h = bh - b * Hn;
#pragma unroll
    for (int qg = 0; qg < 2; ++qg) {
#pragma unroll
      for (int r = 0; r < 4; ++r) {
        const int qo = qb + qg * 16 + lg * 4 + r;   // always < Nn
        const float dinv = 1.0f / (dacc[qg][r] - (float)NPADQ);
#pragma unroll
        for (int ds = 0; ds < 4; ++ds)
          attn[((size_t)(b * Nn + qo)) * Cn + h * HDn + ds * 16 + ln] =
              f2bf(oacc[ds][qg][r] * dinv);
      }
    }
  } else {
    // ================= prefix block: 8 real q rows, m-split over waves ====
    const int i = bid - 768;
    const int bh = (i & 7) * 12 + (i >> 3);    // XCD-affine with patch blocks
    const char* ksrc = (const char*)(khead + (size_t)bh * NQPc * HDn);
    const char* vsrc = (const char*)(vT + (size_t)bh * HDn * NVM);
    const char* qp = (const char*)(khead + ((size_t)bh * NQPc + ln) * HDn);
    bf16x8 qf[2];
    qf[0] = *(const bf16x8*)(qp + lg * 16);
    qf[1] = *(const bf16x8*)(qp + 64 + lg * 16);

    f32x4 oacc[4] = {};
    f32x4 dacc = {};
    for (int mc = w; mc < 17; mc += 4) {       // wave-strided m tiles, no barriers
      const int mb = mc * 64;
      f32x4 sacc[4] = {};
#pragma unroll
      for (int ms = 0; ms < 4; ++ms) {
        const char* kp = ksrc + (size_t)(mb + ms * 16 + ln) * 128 + lg * 16;
        bf16x8 kf0 = *(const bf16x8*)(kp);
        bf16x8 kf1 = *(const bf16x8*)(kp + 64);
        sacc[ms] = __builtin_amdgcn_mfma_f32_16x16x32_bf16(kf0, qf[0], sacc[ms], 0, 0, 0);
        sacc[ms] = __builtin_amdgcn_mfma_f32_16x16x32_bf16(kf1, qf[1], sacc[ms], 0, 0, 0);
      }
      // P = exp2(S*c1): no gauss for prefix q (add rows are zero)
#pragma unroll
      for (int ms = 0; ms < 4; ++ms) {
        bf16x4 pk;
        pk[0] = (__bf16)EXP2(sacc[ms][0] * C1c);
        pk[1] = (__bf16)EXP2(sacc[ms][1] * C1c);
        pk[2] = (__bf16)EXP2(sacc[ms][2] * C1c);
        pk[3] = (__bf16)EXP2(sacc[ms][3] * C1c);
        *(bf16x4*)(sP[w] + ln * 128 + ((ms * 32 + lg * 8) ^ ((ln & 7) << 4))) = pk;
      }
      bf16x8 pf[2];
#pragma unroll
      for (int km = 0; km < 2; ++km)
        pf[km] = *(const bf16x8*)(sP[w] + ln * 128 + ((km * 64 + lg * 16) ^ ((ln & 7) << 4)));
      dacc = __builtin_amdgcn_mfma_f32_16x16x32_bf16(pf[0], ones8, dacc, 0, 0, 0);
      dacc = __builtin_amdgcn_mfma_f32_16x16x32_bf16(pf[1], ones8, dacc, 0, 0, 0);
#pragma unroll
      for (int ds = 0; ds < 4; ++ds) {
        const char* vp = vsrc + (size_t)(ds * 16 + ln) * (NVM * 2) + mb * 2 + lg * 16;
#pragma unroll
        for (int km = 0; km < 2; ++km) {
          bf16x8 vf = *(const bf16x8*)(vp + km * 64);
          oacc[ds] = __builtin_amdgcn_mfma_f32_16x16x32_bf16(pf[km], vf, oacc[ds], 0, 0, 0);
        }
      }
    }
    // merge partials across waves via LDS (sK: 16KB oacc, sV: 4KB dacc)
    char* sKf = (char*)sK;
    char* sVf = (char*)sV;
    __syncthreads();
#pragma unroll
    for (int ds = 0; ds < 4; ++ds)
      *(f32x4*)(sKf + (((w * 4 + ds) * 64 + lane) << 4)) = oacc[ds];
    *(f32x4*)(sVf + ((w * 64 + lane) << 4)) = dacc;
    __syncthreads();
    f32x4 osum = {}, dsum = {};
#pragma unroll
    for (int wp = 0; wp < 4; ++wp) {
      osum += *(const f32x4*)(sKf + (((wp * 4 + w) * 64 + lane) << 4));
      dsum += *(const f32x4*)(sVf + ((wp * 64 + lane) << 4));
    }
    const int b = bh / Hn, h = bh - b * Hn;
#pragma unroll
    for (int r = 0; r < 4; ++r) {
      const int q = lg * 4 + r;
      if (q < PFXc)
        attn[((size_t)(b * Nn + q)) * Cn + h * HDn + w * 16 + ln] =
            f2bf(osum[r] / (dsum[r] - (float)NPADQ));
    }
  }
}

// ---------------- kernel C: out = attn @ w_proj^T + b_proj ----------------
// 1D grid 390 blocks, bijective XCD chunking
__global__ __launch_bounds__(256) void proj_gemm(
    const u16* __restrict__ at, const u16* __restrict__ wpb,
    const float* __restrict__ bproj, float* __restrict__ out) {
  __shared__ __align__(16) char sA[16384];
  __shared__ __align__(16) char sB[16384];
  const int bid = blockIdx.x;                 // 390 = 8*48 + 6
  const int xcd = bid & 7, loc = bid >> 3;
  const int wgid = (xcd < 6) ? xcd * 49 + loc : 294 + (xcd - 6) * 48 + loc;
  const int m0 = (wgid / 6) * 128, n0 = (wgid % 6) * 128;
  f32x4 acc[4][4] = {};
  gemm_mainloop(at, wpb, m0, n0, sA, sB, acc);
  const int tid = threadIdx.x, lane = tid & 63, w = tid >> 6;
  const int ln = lane & 15, lg = lane >> 4;
  const int wm = (w >> 1) * 64, wn = (w & 1) * 64;
#pragma unroll
  for (int t = 0; t < 4; ++t) {
    const int n = n0 + wn + t * 16 + ln;
    const float bias = bproj[n];
#pragma unroll
    for (int s = 0; s < 4; ++s) {
#pragma unroll
      for (int r = 0; r < 4; ++r) {
        const int m = m0 + wm + s * 16 + lg * 4 + r;
        if (m < MTOT) out[(size_t)m * Cn + n] = acc[s][t][r] + bias;
      }
    }
  }
}

extern "C" void kernel_launch(void* const* d_in, const int* in_sizes, int n_in,
                              void* d_out, int out_size, void* d_ws, size_t ws_size,
                              hipStream_t stream) {
  const float* x     = (const float*)d_in[0];
  const float* wqkv  = (const float*)d_in[1];
  const float* bqkv  = (const float*)d_in[2];
  const float* wproj = (const float*)d_in[3];
  const float* bproj = (const float*)d_in[4];
  char* ws = (char*)d_ws;
  u16* xb    = (u16*)(ws + OFF_XB);
  u16* wkvb  = (u16*)(ws + OFF_WKV);
  u16* wpb   = (u16*)(ws + OFF_WP);
  u16* khead = (u16*)(ws + OFF_K);
  u16* vT    = (u16*)(ws + OFF_V);
  u16* attn  = (u16*)(ws + OFF_AT);    // aliases xb (xb dead by then)

  prep_kernel<<<2048, 256, 0, stream>>>(x, wqkv, wproj, xb, wkvb, wpb, khead, vT);
  kv_gemm<<<780, 256, 0, stream>>>(xb, wkvb, bqkv, khead, vT);
  attn_kernel<<<864, 256, 0, stream>>>(khead, vT, attn);
  proj_gemm<<<390, 256, 0, stream>>>(attn, wpb, bproj, (float*)d_out);
}